// Round 1
// baseline (1573.171 us; speedup 1.0000x reference)
//
#include <hip/hip_runtime.h>
#include <hip/hip_bf16.h>
#include <math.h>

// Problem constants (from reference)
#define BATCH 2
#define NTOK  2048
#define DIMC  1024
#define NH    16
#define HD    64
#define QKSCALE 0.125f   // HD^-0.5

// ---------------------------------------------------------------------------
// C[m,n] = sum_k A[m,k] * B[n,k]  (+ bias[n])      "NT" GEMM, fp32 baseline
// 64x64 output tile per 256-thread block, 4x4 per thread, K-tile = 16.
// ---------------------------------------------------------------------------
__global__ __launch_bounds__(256) void gemm_nt_f32(
    const float* __restrict__ A, const float* __restrict__ B,
    const float* __restrict__ bias, float* __restrict__ C,
    int M, int N, int K)
{
    __shared__ float As[16][68];   // [k][m], pad 68 keeps 16B alignment of rows
    __shared__ float Bs[16][68];   // [k][n]

    const int tid  = threadIdx.x;
    const int tx   = tid & 15;          // n sub-tile
    const int ty   = tid >> 4;          // m sub-tile
    const int row0 = blockIdx.y * 64;
    const int col0 = blockIdx.x * 64;

    const int lr = tid >> 2;            // 0..63 : row within tile for loads
    const int lk = (tid & 3) * 4;       // 0,4,8,12 : k offset for loads

    const float* Ap = A + (size_t)(row0 + lr) * K + lk;
    const float* Bp = B + (size_t)(col0 + lr) * K + lk;

    float acc[4][4] = {};

    for (int kt = 0; kt < K; kt += 16) {
        const float4 a = *(const float4*)(Ap + kt);
        const float4 b = *(const float4*)(Bp + kt);
        __syncthreads();   // previous iteration's compute done before overwrite
        As[lk+0][lr] = a.x; As[lk+1][lr] = a.y; As[lk+2][lr] = a.z; As[lk+3][lr] = a.w;
        Bs[lk+0][lr] = b.x; Bs[lk+1][lr] = b.y; Bs[lk+2][lr] = b.z; Bs[lk+3][lr] = b.w;
        __syncthreads();
#pragma unroll
        for (int k = 0; k < 16; ++k) {
            const float4 av = *(const float4*)&As[k][ty * 4];
            const float4 bv = *(const float4*)&Bs[k][tx * 4];
            acc[0][0] += av.x * bv.x; acc[0][1] += av.x * bv.y;
            acc[0][2] += av.x * bv.z; acc[0][3] += av.x * bv.w;
            acc[1][0] += av.y * bv.x; acc[1][1] += av.y * bv.y;
            acc[1][2] += av.y * bv.z; acc[1][3] += av.y * bv.w;
            acc[2][0] += av.z * bv.x; acc[2][1] += av.z * bv.y;
            acc[2][2] += av.z * bv.z; acc[2][3] += av.z * bv.w;
            acc[3][0] += av.w * bv.x; acc[3][1] += av.w * bv.y;
            acc[3][2] += av.w * bv.z; acc[3][3] += av.w * bv.w;
        }
    }

    float4 bv4 = make_float4(0.f, 0.f, 0.f, 0.f);
    if (bias) bv4 = *(const float4*)&bias[col0 + tx * 4];
#pragma unroll
    for (int i = 0; i < 4; ++i) {
        float4 o;
        o.x = acc[i][0] + bv4.x;
        o.y = acc[i][1] + bv4.y;
        o.z = acc[i][2] + bv4.z;
        o.w = acc[i][3] + bv4.w;
        *(float4*)&C[(size_t)(row0 + ty * 4 + i) * N + col0 + tx * 4] = o;
    }
}

// ---------------------------------------------------------------------------
// Flash-style attention, fp32 baseline.
// grid = (N/64, NH, BATCH), block = 256 threads.
// Each block: 64 q-rows of one (b,h). thread = (r = tid&63, qd = tid>>6).
//   - Q row held in registers (16 float4), scaled by QKSCALE at load.
//   - K/V 64-row tiles staged in LDS; online softmax state (m,l) replicated
//     across the 4 threads of a row via LDS reductions.
//   - P tile round-trips through LDS (padded 65 -> conflict-free column reads).
// Output written in [B,N,H*D] layout == reference's transpose+reshape.
// ---------------------------------------------------------------------------
__global__ __launch_bounds__(256) void attn_flash_f32(
    const float* __restrict__ qkv,   // [B, N, 3*DIMC]
    float* __restrict__ att)         // [B, N, DIMC]
{
    const int n0 = blockIdx.x * 64;
    const int h  = blockIdx.y;
    const int b  = blockIdx.z;
    const int tid = threadIdx.x;
    const int r  = tid & 63;    // q row within tile
    const int qd = tid >> 6;    // quarter: which 16 cols / 16 dims this thread owns

    __shared__ float Ks[64][68];   // [krow][d], rows 16B-aligned (68*4=272B)
    __shared__ float Vs[64][68];
    __shared__ float Ps[64][65];   // [qrow][kcol], pad 65 -> banks (r+j)%32
    __shared__ float redm[4][64];
    __shared__ float reds[4][64];

    // Q row -> registers (4 threads per row load redundantly; L1/L2 absorbs)
    float4 qv[16];
    {
        const float* qrow = qkv + (size_t)(b * NTOK + n0 + r) * (3 * DIMC) + h * HD;
#pragma unroll
        for (int i = 0; i < 16; ++i) {
            float4 q = *(const float4*)(qrow + i * 4);
            q.x *= QKSCALE; q.y *= QKSCALE; q.z *= QKSCALE; q.w *= QKSCALE;
            qv[i] = q;
        }
    }

    float m = -INFINITY;
    float l = 0.0f;
    float O[16];
#pragma unroll
    for (int d = 0; d < 16; ++d) O[d] = 0.0f;

    for (int kt0 = 0; kt0 < NTOK; kt0 += 64) {
        // ---- stage K/V tile: 1024 float4 slots per tile, 4 per thread ----
        float4 kstg[4], vstg[4];
#pragma unroll
        for (int t = 0; t < 4; ++t) {
            const int s   = tid + t * 256;
            const int row = s >> 4;
            const int c4  = s & 15;
            const size_t base = (size_t)(b * NTOK + kt0 + row) * (3 * DIMC) + h * HD + c4 * 4;
            kstg[t] = *(const float4*)(qkv + base + DIMC);
            vstg[t] = *(const float4*)(qkv + base + 2 * DIMC);
        }
        __syncthreads();   // previous iteration's LDS reads done
#pragma unroll
        for (int t = 0; t < 4; ++t) {
            const int s   = tid + t * 256;
            const int row = s >> 4;
            const int c4  = s & 15;
            *(float4*)&Ks[row][c4 * 4] = kstg[t];
            *(float4*)&Vs[row][c4 * 4] = vstg[t];
        }
        __syncthreads();

        // ---- S = q . K^T for this thread's 16 columns ----
        float s16[16];
#pragma unroll
        for (int j = 0; j < 16; ++j) s16[j] = 0.0f;
#pragma unroll
        for (int k4 = 0; k4 < 16; ++k4) {
            const float4 q4 = qv[k4];
#pragma unroll
            for (int j = 0; j < 16; ++j) {
                // same address for all lanes of the wave -> broadcast
                const float4 kk = *(const float4*)&Ks[qd * 16 + j][k4 * 4];
                s16[j] += q4.x * kk.x + q4.y * kk.y + q4.z * kk.z + q4.w * kk.w;
            }
        }

        // ---- online softmax: tile max ----
        float lm = s16[0];
#pragma unroll
        for (int j = 1; j < 16; ++j) lm = fmaxf(lm, s16[j]);
        redm[qd][r] = lm;
        __syncthreads();
        const float tmax  = fmaxf(fmaxf(redm[0][r], redm[1][r]),
                                  fmaxf(redm[2][r], redm[3][r]));
        const float m_new = fmaxf(m, tmax);
        const float alpha = __expf(m - m_new);   // first tile: exp(-inf)=0

        float psum = 0.0f;
#pragma unroll
        for (int j = 0; j < 16; ++j) {
            const float p = __expf(s16[j] - m_new);
            Ps[r][qd * 16 + j] = p;
            psum += p;
        }
        reds[qd][r] = psum;
        __syncthreads();   // Ps + reds visible
        const float tsum = reds[0][r] + reds[1][r] + reds[2][r] + reds[3][r];
        l = l * alpha + tsum;
        m = m_new;

        // ---- O = O*alpha + P . V  (this thread's 16 dims: d = qd*16 + dd) ----
#pragma unroll
        for (int d = 0; d < 16; ++d) O[d] *= alpha;
        for (int j = 0; j < 64; ++j) {
            const float p = Ps[r][j];               // banks (r+j)%32: conflict-free
#pragma unroll
            for (int c = 0; c < 4; ++c) {
                const float4 vv = *(const float4*)&Vs[j][qd * 16 + c * 4]; // broadcast
                O[c * 4 + 0] += p * vv.x;
                O[c * 4 + 1] += p * vv.y;
                O[c * 4 + 2] += p * vv.z;
                O[c * 4 + 3] += p * vv.w;
            }
        }
        __syncthreads();   // all reads of Ks/Vs/Ps done before next stage
    }

    const float inv_l = 1.0f / l;
    float* orow = att + (size_t)(b * NTOK + n0 + r) * DIMC + h * HD + qd * 16;
#pragma unroll
    for (int c = 0; c < 4; ++c) {
        float4 o;
        o.x = O[c * 4 + 0] * inv_l;
        o.y = O[c * 4 + 1] * inv_l;
        o.z = O[c * 4 + 2] * inv_l;
        o.w = O[c * 4 + 3] * inv_l;
        *(float4*)(orow + c * 4) = o;
    }
}

// ---------------------------------------------------------------------------
extern "C" void kernel_launch(void* const* d_in, const int* in_sizes, int n_in,
                              void* d_out, int out_size, void* d_ws, size_t ws_size,
                              hipStream_t stream)
{
    const float* x      = (const float*)d_in[0];   // [2,2048,1024]
    const float* W_qkv  = (const float*)d_in[1];   // [3072,1024]
    const float* W_proj = (const float*)d_in[2];   // [1024,1024]
    const float* b_proj = (const float*)d_in[3];   // [1024]
    float* out = (float*)d_out;                    // [2,2048,1024]

    // workspace: qkv [4096,3072] fp32 (48 MiB) + att [4096,1024] fp32 (16 MiB)
    float* qkv = (float*)d_ws;
    float* att = qkv + (size_t)(BATCH * NTOK) * (3 * DIMC);

    const int M = BATCH * NTOK;   // 4096

    // 1) qkv = x @ W_qkv^T
    gemm_nt_f32<<<dim3((3 * DIMC) / 64, M / 64), 256, 0, stream>>>(
        x, W_qkv, nullptr, qkv, M, 3 * DIMC, DIMC);

    // 2) flash attention per (b,h), 64 q-rows per block
    attn_flash_f32<<<dim3(NTOK / 64, NH, BATCH), 256, 0, stream>>>(qkv, att);

    // 3) out = att @ W_proj^T + b_proj
    gemm_nt_f32<<<dim3(DIMC / 64, M / 64), 256, 0, stream>>>(
        att, W_proj, b_proj, out, M, DIMC, DIMC);
}